// Round 1
// baseline (1769.391 us; speedup 1.0000x reference)
//
#include <hip/hip_runtime.h>

// ---------- types ----------
typedef __attribute__((ext_vector_type(8))) short short8;
typedef __attribute__((ext_vector_type(4))) float float4v;
typedef __attribute__((ext_vector_type(4))) unsigned short ushort4v;

__device__ __forceinline__ float bf2f(unsigned short u) {
  union { unsigned int i; float f; } x; x.i = ((unsigned int)u) << 16; return x.f;
}
__device__ __forceinline__ unsigned short f2bf(float f) {
  union { unsigned int i; float f; } x; x.f = f;
  unsigned int r = x.i + 0x7fffu + ((x.i >> 16) & 1u);  // round-nearest-even
  return (unsigned short)(r >> 16);
}

// ---------- LayerNorm: one block per row of 768 ----------
__global__ void ln_kernel(const float* __restrict__ in, const float* __restrict__ g,
                          const float* __restrict__ b, unsigned short* __restrict__ out) {
  const int row = blockIdx.x, t = threadIdx.x;
  const float* xr = in + (size_t)row * 768;
  float v0 = xr[t], v1 = xr[t + 256], v2 = xr[t + 512];
  float s = v0 + v1 + v2;
  float s2 = v0 * v0 + v1 * v1 + v2 * v2;
  for (int off = 32; off > 0; off >>= 1) {
    s += __shfl_xor(s, off, 64);
    s2 += __shfl_xor(s2, off, 64);
  }
  __shared__ float red[8];
  const int wave = t >> 6, lane = t & 63;
  if (lane == 0) { red[wave] = s; red[wave + 4] = s2; }
  __syncthreads();
  s = red[0] + red[1] + red[2] + red[3];
  s2 = red[4] + red[5] + red[6] + red[7];
  const float mu = s * (1.0f / 768.0f);
  const float var = s2 * (1.0f / 768.0f) - mu * mu;
  const float rstd = rsqrtf(var + 1e-5f);
  unsigned short* orow = out + (size_t)row * 768;
  orow[t]       = f2bf((v0 - mu) * rstd * g[t]       + b[t]);
  orow[t + 256] = f2bf((v1 - mu) * rstd * g[t + 256] + b[t + 256]);
  orow[t + 512] = f2bf((v2 - mu) * rstd * g[t + 512] + b[t + 512]);
}

// ---------- GEMM core: 64x64 tile per 256-thread block, bf16 MFMA ----------
// A: bf16 row-major MxK (lda=K). B: f32 row-major KxN (ldb=N), converted to bf16 on stage.
// Wave w owns rows [16w,16w+16); acc[nt] covers cols [nt*16, nt*16+16).
// C/D layout (verified m89): row = (lane>>4)*4 + reg, col = lane&15.
// A frag: A[m=lane&15][k=(lane>>4)*8+j]; B frag: B[n=lane&15][k=(lane>>4)*8+j] (n-major LDS).
#define LDSS 40  // 32 + 8 pad, keeps 16B alignment for short8 reads

__device__ __forceinline__ void gemm_tile(
    const unsigned short* __restrict__ A, int lda,
    const float* __restrict__ B, int ldb, int K,
    int row0, int col0,
    unsigned short* As, unsigned short* Bs,
    float4v acc[4]) {
  const int t = threadIdx.x;
  const int lane = t & 63, wave = t >> 6;
  const int quad = lane >> 4, l16 = lane & 15;
  const int arow = t >> 2, acol = (t & 3) * 8;   // A stage: 64 rows x 32 k
  const int bk = t & 31, bn = (t >> 5) * 8;      // B stage: k x 8 n's, transposed into LDS
  acc[0] = (float4v)(0.0f); acc[1] = (float4v)(0.0f);
  acc[2] = (float4v)(0.0f); acc[3] = (float4v)(0.0f);
  for (int kk = 0; kk < K; kk += 32) {
    short8 av = *(const short8*)(A + (size_t)(row0 + arow) * lda + kk + acol);
    const float* bp = B + (size_t)(kk + bk) * ldb + col0 + bn;
    float4 b0 = *(const float4*)bp;
    float4 b1 = *(const float4*)(bp + 4);
    *(short8*)(As + arow * LDSS + acol) = av;
    unsigned short* bw = Bs + bn * LDSS + bk;
    bw[0 * LDSS] = f2bf(b0.x); bw[1 * LDSS] = f2bf(b0.y);
    bw[2 * LDSS] = f2bf(b0.z); bw[3 * LDSS] = f2bf(b0.w);
    bw[4 * LDSS] = f2bf(b1.x); bw[5 * LDSS] = f2bf(b1.y);
    bw[6 * LDSS] = f2bf(b1.z); bw[7 * LDSS] = f2bf(b1.w);
    __syncthreads();
    short8 a = *(const short8*)(As + (wave * 16 + l16) * LDSS + quad * 8);
#pragma unroll
    for (int nt = 0; nt < 4; ++nt) {
      short8 bf = *(const short8*)(Bs + (nt * 16 + l16) * LDSS + quad * 8);
      acc[nt] = __builtin_amdgcn_mfma_f32_16x16x32_bf16(a, bf, acc[nt], 0, 0, 0);
    }
    __syncthreads();
  }
}

#define GEMM_EPILOGUE_IDX                                        \
  const int t = threadIdx.x, lane = t & 63, wave = t >> 6;       \
  const int quad = lane >> 4, l16 = lane & 15;                   \
  (void)t;

// ---------- kv GEMM: xn @ w_kv -> k,v in (B,H,N,DH) bf16 ----------
__global__ void gemm_kv_kernel(const unsigned short* __restrict__ xn,
                               const float* __restrict__ w_kv,
                               unsigned short* __restrict__ kbuf,
                               unsigned short* __restrict__ vbuf) {
  __shared__ unsigned short As[64 * LDSS];
  __shared__ unsigned short Bs[64 * LDSS];
  float4v acc[4];
  const int col0 = blockIdx.x * 64, row0 = blockIdx.y * 64;
  gemm_tile(xn, 768, w_kv, 1536, 768, row0, col0, As, Bs, acc);
  GEMM_EPILOGUE_IDX
#pragma unroll
  for (int nt = 0; nt < 4; ++nt) {
    const int j = col0 + nt * 16 + l16;
#pragma unroll
    for (int r = 0; r < 4; ++r) {
      const int m = row0 + wave * 16 + quad * 4 + r;
      const int bb = m >> 10, n = m & 1023;
      const float c = acc[nt][r];
      if (j < 768) {
        const int hh = j >> 6, d = j & 63;
        kbuf[((size_t)(bb * 12 + hh) * 1024 + n) * 64 + d] = f2bf(c);
      } else {
        const int j2 = j - 768, hh = j2 >> 6, d = j2 & 63;
        vbuf[((size_t)(bb * 12 + hh) * 1024 + n) * 64 + d] = f2bf(c);
      }
    }
  }
}

// ---------- attention: block = (8 q-rows, one (b,h)); two-pass softmax ----------
__global__ void attn_kernel(const float* __restrict__ q_extra,
                            const unsigned short* __restrict__ kbuf,
                            const unsigned short* __restrict__ vbuf,
                            unsigned short* __restrict__ ao) {
  __shared__ float qs[8 * 64];
  __shared__ unsigned short ks[128 * 66];  // 66-stride: 2-way bank alias only (free)
  __shared__ float sc[8 * 1024];
  __shared__ float rowinv[8];
  const int b = blockIdx.z, h = blockIdx.y, r0 = blockIdx.x * 8;
  const int t = threadIdx.x, lane = t & 63, wave = t >> 6;
  for (int i = t; i < 512; i += 256) {
    const int r = i >> 6, d = i & 63;
    qs[i] = q_extra[((size_t)(b * 1024 + r0 + r) * 12 + h) * 64 + d];
  }
  const unsigned short* kb = kbuf + (size_t)(b * 12 + h) * 65536;
  const unsigned short* vb = vbuf + (size_t)(b * 12 + h) * 65536;
  const int myj = t & 127, rg = (t >> 7) * 4;
  // phase A: scores
  for (int j0 = 0; j0 < 1024; j0 += 128) {
    __syncthreads();
    for (int i = t; i < 2048; i += 256) {
      const int jr = i >> 4, off = (i & 15) * 4;
      ushort4v val = *(const ushort4v*)(kb + (size_t)(j0 + jr) * 64 + off);
      unsigned short* dst = ks + jr * 66 + off;
      dst[0] = val.x; dst[1] = val.y; dst[2] = val.z; dst[3] = val.w;
    }
    __syncthreads();
    float d0 = 0.f, d1 = 0.f, d2 = 0.f, d3 = 0.f;
    const unsigned short* kr = ks + myj * 66;
#pragma unroll 8
    for (int d = 0; d < 64; ++d) {
      const float kv = bf2f(kr[d]);
      d0 += qs[(rg + 0) * 64 + d] * kv;
      d1 += qs[(rg + 1) * 64 + d] * kv;
      d2 += qs[(rg + 2) * 64 + d] * kv;
      d3 += qs[(rg + 3) * 64 + d] * kv;
    }
    sc[(rg + 0) * 1024 + j0 + myj] = d0 * 0.125f;
    sc[(rg + 1) * 1024 + j0 + myj] = d1 * 0.125f;
    sc[(rg + 2) * 1024 + j0 + myj] = d2 * 0.125f;
    sc[(rg + 3) * 1024 + j0 + myj] = d3 * 0.125f;
  }
  __syncthreads();
  // phase B: softmax (wave w: rows w, w+4)
#pragma unroll
  for (int rr = 0; rr < 2; ++rr) {
    const int r = wave + rr * 4;
    float m = -1e30f;
    for (int j = lane; j < 1024; j += 64) m = fmaxf(m, sc[r * 1024 + j]);
    for (int off = 32; off > 0; off >>= 1) m = fmaxf(m, __shfl_xor(m, off, 64));
    float s = 0.0f;
    for (int j = lane; j < 1024; j += 64) {
      const float p = expf(sc[r * 1024 + j] - m);
      sc[r * 1024 + j] = p;
      s += p;
    }
    for (int off = 32; off > 0; off >>= 1) s += __shfl_xor(s, off, 64);
    if (lane == 0) rowinv[r] = 1.0f / s;
  }
  __syncthreads();
  // phase C: P @ V
  const int d = t & 63, rgrp = wave;
  float a0 = 0.f, a1 = 0.f;
  for (int j0 = 0; j0 < 1024; j0 += 128) {
    __syncthreads();
    for (int i = t; i < 2048; i += 256) {
      const int jr = i >> 4, off = (i & 15) * 4;
      ushort4v val = *(const ushort4v*)(vb + (size_t)(j0 + jr) * 64 + off);
      unsigned short* dst = ks + jr * 66 + off;
      dst[0] = val.x; dst[1] = val.y; dst[2] = val.z; dst[3] = val.w;
    }
    __syncthreads();
#pragma unroll 8
    for (int jj = 0; jj < 128; ++jj) {
      const float vv = bf2f(ks[jj * 66 + d]);
      a0 += sc[rgrp * 1024 + j0 + jj] * vv;
      a1 += sc[(rgrp + 4) * 1024 + j0 + jj] * vv;
    }
  }
  const size_t base = (size_t)(b * 1024 + r0) * 768 + h * 64 + d;
  ao[base + (size_t)rgrp * 768]       = f2bf(a0 * rowinv[rgrp]);
  ao[base + (size_t)(rgrp + 4) * 768] = f2bf(a1 * rowinv[rgrp + 4]);
}

// ---------- out-proj GEMM + bias + residual -> x2 (f32) ----------
__global__ void gemm_outproj_kernel(const unsigned short* __restrict__ ao,
                                    const float* __restrict__ w_out,
                                    const float* __restrict__ b_out,
                                    const float* __restrict__ x,
                                    float* __restrict__ x2) {
  __shared__ unsigned short As[64 * LDSS];
  __shared__ unsigned short Bs[64 * LDSS];
  float4v acc[4];
  const int col0 = blockIdx.x * 64, row0 = blockIdx.y * 64;
  gemm_tile(ao, 768, w_out, 768, 768, row0, col0, As, Bs, acc);
  GEMM_EPILOGUE_IDX
#pragma unroll
  for (int nt = 0; nt < 4; ++nt) {
    const int j = col0 + nt * 16 + l16;
#pragma unroll
    for (int r = 0; r < 4; ++r) {
      const int m = row0 + wave * 16 + quad * 4 + r;
      const size_t idx = (size_t)m * 768 + j;
      x2[idx] = acc[nt][r] + b_out[j] + x[idx];
    }
  }
}

// ---------- MLP1 GEMM + bias + exact GELU -> h1 (bf16) ----------
__global__ void gemm_mlp1_kernel(const unsigned short* __restrict__ h,
                                 const float* __restrict__ w1,
                                 const float* __restrict__ b1,
                                 unsigned short* __restrict__ h1) {
  __shared__ unsigned short As[64 * LDSS];
  __shared__ unsigned short Bs[64 * LDSS];
  float4v acc[4];
  const int col0 = blockIdx.x * 64, row0 = blockIdx.y * 64;
  gemm_tile(h, 768, w1, 3072, 768, row0, col0, As, Bs, acc);
  GEMM_EPILOGUE_IDX
#pragma unroll
  for (int nt = 0; nt < 4; ++nt) {
    const int j = col0 + nt * 16 + l16;
#pragma unroll
    for (int r = 0; r < 4; ++r) {
      const int m = row0 + wave * 16 + quad * 4 + r;
      const float y = acc[nt][r] + b1[j];
      const float ge = 0.5f * y * (1.0f + erff(y * 0.70710678118654752f));
      h1[(size_t)m * 3072 + j] = f2bf(ge);
    }
  }
}

// ---------- MLP2 GEMM + bias + residual -> out (f32) ----------
__global__ void gemm_mlp2_kernel(const unsigned short* __restrict__ h1,
                                 const float* __restrict__ w2,
                                 const float* __restrict__ b2,
                                 const float* __restrict__ x2,
                                 float* __restrict__ out) {
  __shared__ unsigned short As[64 * LDSS];
  __shared__ unsigned short Bs[64 * LDSS];
  float4v acc[4];
  const int col0 = blockIdx.x * 64, row0 = blockIdx.y * 64;
  gemm_tile(h1, 3072, w2, 768, 3072, row0, col0, As, Bs, acc);
  GEMM_EPILOGUE_IDX
#pragma unroll
  for (int nt = 0; nt < 4; ++nt) {
    const int j = col0 + nt * 16 + l16;
#pragma unroll
    for (int r = 0; r < 4; ++r) {
      const int m = row0 + wave * 16 + quad * 4 + r;
      const size_t idx = (size_t)m * 768 + j;
      out[idx] = acc[nt][r] + b2[j] + x2[idx];
    }
  }
}

// ---------- launch ----------
extern "C" void kernel_launch(void* const* d_in, const int* in_sizes, int n_in,
                              void* d_out, int out_size, void* d_ws, size_t ws_size,
                              hipStream_t stream) {
  const float* x       = (const float*)d_in[0];
  const float* q_extra = (const float*)d_in[1];
  const float* ln1_g   = (const float*)d_in[2];
  const float* ln1_b   = (const float*)d_in[3];
  const float* w_kv    = (const float*)d_in[4];
  const float* w_out   = (const float*)d_in[5];
  const float* b_out   = (const float*)d_in[6];
  const float* ln2_g   = (const float*)d_in[7];
  const float* ln2_b   = (const float*)d_in[8];
  const float* w1      = (const float*)d_in[9];
  const float* b1      = (const float*)d_in[10];
  const float* w2      = (const float*)d_in[11];
  const float* b2      = (const float*)d_in[12];
  float* out = (float*)d_out;

  char* ws = (char*)d_ws;
  // layout (bytes): xn/h bf16 12.58M | k 12.58M | v 12.58M | ao 12.58M | x2 f32 25.17M | h1 bf16 50.33M
  unsigned short* xn   = (unsigned short*)(ws);
  unsigned short* kbuf = (unsigned short*)(ws + 12582912);
  unsigned short* vbuf = (unsigned short*)(ws + 25165824);
  unsigned short* ao   = (unsigned short*)(ws + 37748736);
  float*          x2   = (float*)(ws + 50331648);
  unsigned short* h1   = (unsigned short*)(ws + 75497472);
  unsigned short* hbuf = xn;  // xn dead after kv GEMM; reuse for LN2 output

  ln_kernel<<<8192, 256, 0, stream>>>(x, ln1_g, ln1_b, xn);
  gemm_kv_kernel<<<dim3(24, 128), 256, 0, stream>>>(xn, w_kv, kbuf, vbuf);
  attn_kernel<<<dim3(128, 12, 8), 256, 0, stream>>>(q_extra, kbuf, vbuf, ao);
  gemm_outproj_kernel<<<dim3(12, 128), 256, 0, stream>>>(ao, w_out, b_out, x, x2);
  ln_kernel<<<8192, 256, 0, stream>>>(x2, ln2_g, ln2_b, hbuf);
  gemm_mlp1_kernel<<<dim3(48, 128), 256, 0, stream>>>(hbuf, w1, b1, h1);
  gemm_mlp2_kernel<<<dim3(12, 128), 256, 0, stream>>>(h1, w2, b2, x2, out);
}

// Round 2
// 707.534 us; speedup vs baseline: 2.5008x; 2.5008x over previous
//
#include <hip/hip_runtime.h>

// ---------- types ----------
typedef __attribute__((ext_vector_type(8))) short short8;
typedef __attribute__((ext_vector_type(4))) float float4v;

__device__ __forceinline__ float bf2f(unsigned short u) {
  union { unsigned int i; float f; } x; x.i = ((unsigned int)u) << 16; return x.f;
}
__device__ __forceinline__ unsigned short f2bf(float f) {
  union { unsigned int i; float f; } x; x.f = f;
  unsigned int r = x.i + 0x7fffu + ((x.i >> 16) & 1u);  // round-nearest-even
  return (unsigned short)(r >> 16);
}

// ---------- LayerNorm: one block per row of 768 ----------
__global__ void ln_kernel(const float* __restrict__ in, const float* __restrict__ g,
                          const float* __restrict__ b, unsigned short* __restrict__ out) {
  const int row = blockIdx.x, t = threadIdx.x;
  const float* xr = in + (size_t)row * 768;
  float v0 = xr[t], v1 = xr[t + 256], v2 = xr[t + 512];
  float s = v0 + v1 + v2;
  float s2 = v0 * v0 + v1 * v1 + v2 * v2;
  for (int off = 32; off > 0; off >>= 1) {
    s += __shfl_xor(s, off, 64);
    s2 += __shfl_xor(s2, off, 64);
  }
  __shared__ float red[8];
  const int wave = t >> 6, lane = t & 63;
  if (lane == 0) { red[wave] = s; red[wave + 4] = s2; }
  __syncthreads();
  s = red[0] + red[1] + red[2] + red[3];
  s2 = red[4] + red[5] + red[6] + red[7];
  const float mu = s * (1.0f / 768.0f);
  const float var = s2 * (1.0f / 768.0f) - mu * mu;
  const float rstd = rsqrtf(var + 1e-5f);
  unsigned short* orow = out + (size_t)row * 768;
  orow[t]       = f2bf((v0 - mu) * rstd * g[t]       + b[t]);
  orow[t + 256] = f2bf((v1 - mu) * rstd * g[t + 256] + b[t + 256]);
  orow[t + 512] = f2bf((v2 - mu) * rstd * g[t + 512] + b[t + 512]);
}

// ---------- GEMM core: 64x64 tile per 256-thread block, bf16 MFMA ----------
#define LDSS 40  // 32 + 8 pad, keeps 16B alignment for short8 reads

__device__ __forceinline__ void gemm_tile(
    const unsigned short* __restrict__ A, int lda,
    const float* __restrict__ B, int ldb, int K,
    int row0, int col0,
    unsigned short* As, unsigned short* Bs,
    float4v acc[4]) {
  const int t = threadIdx.x;
  const int lane = t & 63, wave = t >> 6;
  const int quad = lane >> 4, l16 = lane & 15;
  const int arow = t >> 2, acol = (t & 3) * 8;   // A stage: 64 rows x 32 k
  const int bk = t & 31, bn = (t >> 5) * 8;      // B stage: k x 8 n's, transposed into LDS
  acc[0] = (float4v)(0.0f); acc[1] = (float4v)(0.0f);
  acc[2] = (float4v)(0.0f); acc[3] = (float4v)(0.0f);
  for (int kk = 0; kk < K; kk += 32) {
    short8 av = *(const short8*)(A + (size_t)(row0 + arow) * lda + kk + acol);
    const float* bp = B + (size_t)(kk + bk) * ldb + col0 + bn;
    float4 b0 = *(const float4*)bp;
    float4 b1 = *(const float4*)(bp + 4);
    *(short8*)(As + arow * LDSS + acol) = av;
    unsigned short* bw = Bs + bn * LDSS + bk;
    bw[0 * LDSS] = f2bf(b0.x); bw[1 * LDSS] = f2bf(b0.y);
    bw[2 * LDSS] = f2bf(b0.z); bw[3 * LDSS] = f2bf(b0.w);
    bw[4 * LDSS] = f2bf(b1.x); bw[5 * LDSS] = f2bf(b1.y);
    bw[6 * LDSS] = f2bf(b1.z); bw[7 * LDSS] = f2bf(b1.w);
    __syncthreads();
    short8 a = *(const short8*)(As + (wave * 16 + l16) * LDSS + quad * 8);
#pragma unroll
    for (int nt = 0; nt < 4; ++nt) {
      short8 bf = *(const short8*)(Bs + (nt * 16 + l16) * LDSS + quad * 8);
      acc[nt] = __builtin_amdgcn_mfma_f32_16x16x32_bf16(a, bf, acc[nt], 0, 0, 0);
    }
    __syncthreads();
  }
}

#define GEMM_EPILOGUE_IDX                                        \
  const int t = threadIdx.x, lane = t & 63, wave = t >> 6;       \
  const int quad = lane >> 4, l16 = lane & 15;                   \
  (void)t;

// ---------- kv GEMM: xn @ w_kv -> k (B,H,N,DH), v TRANSPOSED (B,H,DH,N) ----------
__global__ void gemm_kv_kernel(const unsigned short* __restrict__ xn,
                               const float* __restrict__ w_kv,
                               unsigned short* __restrict__ kbuf,
                               unsigned short* __restrict__ vtbuf) {
  __shared__ unsigned short As[64 * LDSS];
  __shared__ unsigned short Bs[64 * LDSS];
  float4v acc[4];
  const int col0 = blockIdx.x * 64, row0 = blockIdx.y * 64;
  gemm_tile(xn, 768, w_kv, 1536, 768, row0, col0, As, Bs, acc);
  GEMM_EPILOGUE_IDX
#pragma unroll
  for (int nt = 0; nt < 4; ++nt) {
    const int j = col0 + nt * 16 + l16;
#pragma unroll
    for (int r = 0; r < 4; ++r) {
      const int m = row0 + wave * 16 + quad * 4 + r;
      const int bb = m >> 10, n = m & 1023;
      const float c = acc[nt][r];
      if (j < 768) {
        const int hh = j >> 6, d = j & 63;
        kbuf[((size_t)(bb * 12 + hh) * 1024 + n) * 64 + d] = f2bf(c);
      } else {
        const int j2 = j - 768, hh = j2 >> 6, d = j2 & 63;
        vtbuf[((size_t)(bb * 12 + hh) * 64 + d) * 1024 + n] = f2bf(c);
      }
    }
  }
}

// ---------- MFMA flash attention ----------
// Block = (b, h, 64 q rows); 4 waves x 16 q rows. Key chunks of 64.
// S=Q@K^T via 16x16x32 bf16 MFMA; online softmax on C-layout frags;
// P -> LDS -> A-layout frags; O += P@V with V^T staged in LDS.
#define AST 72  // 64 + 8 pad (2-way bank alias only; keeps 16B align)
__global__ void attn_kernel(const float* __restrict__ q_extra,
                            const unsigned short* __restrict__ kbuf,
                            const unsigned short* __restrict__ vtbuf,
                            unsigned short* __restrict__ ao) {
  __shared__ unsigned short Ks[64 * AST];
  __shared__ unsigned short Vs[64 * AST];
  __shared__ unsigned short Ps[4][16 * AST];
  const int b = blockIdx.z, h = blockIdx.y, q0 = blockIdx.x * 64;
  const int t = threadIdx.x, lane = t & 63, wave = t >> 6;
  const int quad = lane >> 4, l16 = lane & 15;

  // Q fragments (A-layout), pre-scaled by softmax scale 1/8 (exact pow2)
  short8 qf0, qf1;
  {
    const float* qp = q_extra +
        ((size_t)((b * 1024 + q0 + wave * 16 + l16) * 12 + h)) * 64 + quad * 8;
    float4 a0 = *(const float4*)(qp);
    float4 a1 = *(const float4*)(qp + 4);
    float4 c0 = *(const float4*)(qp + 32);
    float4 c1 = *(const float4*)(qp + 36);
    qf0[0] = (short)f2bf(a0.x * 0.125f); qf0[1] = (short)f2bf(a0.y * 0.125f);
    qf0[2] = (short)f2bf(a0.z * 0.125f); qf0[3] = (short)f2bf(a0.w * 0.125f);
    qf0[4] = (short)f2bf(a1.x * 0.125f); qf0[5] = (short)f2bf(a1.y * 0.125f);
    qf0[6] = (short)f2bf(a1.z * 0.125f); qf0[7] = (short)f2bf(a1.w * 0.125f);
    qf1[0] = (short)f2bf(c0.x * 0.125f); qf1[1] = (short)f2bf(c0.y * 0.125f);
    qf1[2] = (short)f2bf(c0.z * 0.125f); qf1[3] = (short)f2bf(c0.w * 0.125f);
    qf1[4] = (short)f2bf(c1.x * 0.125f); qf1[5] = (short)f2bf(c1.y * 0.125f);
    qf1[6] = (short)f2bf(c1.z * 0.125f); qf1[7] = (short)f2bf(c1.w * 0.125f);
  }

  const unsigned short* kb = kbuf + (size_t)(b * 12 + h) * 65536;
  const unsigned short* vb = vtbuf + (size_t)(b * 12 + h) * 65536;
  const int srow = t >> 2, scol = (t & 3) * 16;

  float m_r[4] = {-1e30f, -1e30f, -1e30f, -1e30f};
  float l_r[4] = {0.f, 0.f, 0.f, 0.f};
  float4v acc[4];
  acc[0] = (float4v)(0.f); acc[1] = (float4v)(0.f);
  acc[2] = (float4v)(0.f); acc[3] = (float4v)(0.f);

  for (int c = 0; c < 16; ++c) {
    const int key0 = c * 64;
    __syncthreads();  // protect Ks/Vs from previous iteration's readers
    {
      const unsigned short* ksrc = kb + (size_t)(key0 + srow) * 64 + scol;
      *(short8*)(Ks + srow * AST + scol)     = *(const short8*)(ksrc);
      *(short8*)(Ks + srow * AST + scol + 8) = *(const short8*)(ksrc + 8);
      const unsigned short* vsrc = vb + (size_t)srow * 1024 + key0 + scol;
      *(short8*)(Vs + srow * AST + scol)     = *(const short8*)(vsrc);
      *(short8*)(Vs + srow * AST + scol + 8) = *(const short8*)(vsrc + 8);
    }
    __syncthreads();

    // S = Q @ K^T : 4 tiles of 16 keys
    float4v s[4];
#pragma unroll
    for (int kt = 0; kt < 4; ++kt) {
      const unsigned short* kr = Ks + (kt * 16 + l16) * AST;
      short8 kf0 = *(const short8*)(kr + quad * 8);
      short8 kf1 = *(const short8*)(kr + 32 + quad * 8);
      float4v a = (float4v)(0.f);
      a = __builtin_amdgcn_mfma_f32_16x16x32_bf16(qf0, kf0, a, 0, 0, 0);
      a = __builtin_amdgcn_mfma_f32_16x16x32_bf16(qf1, kf1, a, 0, 0, 0);
      s[kt] = a;
    }

    // online softmax: row = quad*4 + r; cols spread over 16 lanes of the quad
    float mx[4];
#pragma unroll
    for (int r = 0; r < 4; ++r)
      mx[r] = fmaxf(fmaxf(s[0][r], s[1][r]), fmaxf(s[2][r], s[3][r]));
#pragma unroll
    for (int off = 1; off < 16; off <<= 1) {
#pragma unroll
      for (int r = 0; r < 4; ++r) mx[r] = fmaxf(mx[r], __shfl_xor(mx[r], off, 64));
    }
    float alpha[4], sum[4];
#pragma unroll
    for (int r = 0; r < 4; ++r) {
      const float mn = fmaxf(m_r[r], mx[r]);
      alpha[r] = __expf(m_r[r] - mn);
      m_r[r] = mn;
      sum[r] = 0.f;
    }
    unsigned short* pw = Ps[wave];
#pragma unroll
    for (int kt = 0; kt < 4; ++kt) {
#pragma unroll
      for (int r = 0; r < 4; ++r) {
        const float p = __expf(s[kt][r] - m_r[r]);
        sum[r] += p;
        pw[(quad * 4 + r) * AST + kt * 16 + l16] = f2bf(p);
      }
    }
#pragma unroll
    for (int off = 1; off < 16; off <<= 1) {
#pragma unroll
      for (int r = 0; r < 4; ++r) sum[r] += __shfl_xor(sum[r], off, 64);
    }
#pragma unroll
    for (int r = 0; r < 4; ++r) l_r[r] = l_r[r] * alpha[r] + sum[r];
#pragma unroll
    for (int nt = 0; nt < 4; ++nt) {
#pragma unroll
      for (int r = 0; r < 4; ++r) acc[nt][r] *= alpha[r];
    }

    // P (A-layout) and O += P @ V
    short8 pf0 = *(const short8*)(pw + l16 * AST + quad * 8);
    short8 pf1 = *(const short8*)(pw + l16 * AST + 32 + quad * 8);
#pragma unroll
    for (int nt = 0; nt < 4; ++nt) {
      const unsigned short* vr = Vs + (nt * 16 + l16) * AST;
      short8 vf0 = *(const short8*)(vr + quad * 8);
      short8 vf1 = *(const short8*)(vr + 32 + quad * 8);
      acc[nt] = __builtin_amdgcn_mfma_f32_16x16x32_bf16(pf0, vf0, acc[nt], 0, 0, 0);
      acc[nt] = __builtin_amdgcn_mfma_f32_16x16x32_bf16(pf1, vf1, acc[nt], 0, 0, 0);
    }
  }

  float inv[4];
#pragma unroll
  for (int r = 0; r < 4; ++r) inv[r] = 1.0f / l_r[r];
#pragma unroll
  for (int nt = 0; nt < 4; ++nt) {
#pragma unroll
    for (int r = 0; r < 4; ++r) {
      const int m = q0 + wave * 16 + quad * 4 + r;
      ao[(size_t)(b * 1024 + m) * 768 + h * 64 + nt * 16 + l16] =
          f2bf(acc[nt][r] * inv[r]);
    }
  }
}

// ---------- out-proj GEMM + bias + residual -> x2 (f32) ----------
__global__ void gemm_outproj_kernel(const unsigned short* __restrict__ ao,
                                    const float* __restrict__ w_out,
                                    const float* __restrict__ b_out,
                                    const float* __restrict__ x,
                                    float* __restrict__ x2) {
  __shared__ unsigned short As[64 * LDSS];
  __shared__ unsigned short Bs[64 * LDSS];
  float4v acc[4];
  const int col0 = blockIdx.x * 64, row0 = blockIdx.y * 64;
  gemm_tile(ao, 768, w_out, 768, 768, row0, col0, As, Bs, acc);
  GEMM_EPILOGUE_IDX
#pragma unroll
  for (int nt = 0; nt < 4; ++nt) {
    const int j = col0 + nt * 16 + l16;
#pragma unroll
    for (int r = 0; r < 4; ++r) {
      const int m = row0 + wave * 16 + quad * 4 + r;
      const size_t idx = (size_t)m * 768 + j;
      x2[idx] = acc[nt][r] + b_out[j] + x[idx];
    }
  }
}

// ---------- MLP1 GEMM + bias + exact GELU -> h1 (bf16) ----------
__global__ void gemm_mlp1_kernel(const unsigned short* __restrict__ h,
                                 const float* __restrict__ w1,
                                 const float* __restrict__ b1,
                                 unsigned short* __restrict__ h1) {
  __shared__ unsigned short As[64 * LDSS];
  __shared__ unsigned short Bs[64 * LDSS];
  float4v acc[4];
  const int col0 = blockIdx.x * 64, row0 = blockIdx.y * 64;
  gemm_tile(h, 768, w1, 3072, 768, row0, col0, As, Bs, acc);
  GEMM_EPILOGUE_IDX
#pragma unroll
  for (int nt = 0; nt < 4; ++nt) {
    const int j = col0 + nt * 16 + l16;
#pragma unroll
    for (int r = 0; r < 4; ++r) {
      const int m = row0 + wave * 16 + quad * 4 + r;
      const float y = acc[nt][r] + b1[j];
      const float ge = 0.5f * y * (1.0f + erff(y * 0.70710678118654752f));
      h1[(size_t)m * 3072 + j] = f2bf(ge);
    }
  }
}

// ---------- MLP2 GEMM + bias + residual -> out (f32) ----------
__global__ void gemm_mlp2_kernel(const unsigned short* __restrict__ h1,
                                 const float* __restrict__ w2,
                                 const float* __restrict__ b2,
                                 const float* __restrict__ x2,
                                 float* __restrict__ out) {
  __shared__ unsigned short As[64 * LDSS];
  __shared__ unsigned short Bs[64 * LDSS];
  float4v acc[4];
  const int col0 = blockIdx.x * 64, row0 = blockIdx.y * 64;
  gemm_tile(h1, 3072, w2, 768, 3072, row0, col0, As, Bs, acc);
  GEMM_EPILOGUE_IDX
#pragma unroll
  for (int nt = 0; nt < 4; ++nt) {
    const int j = col0 + nt * 16 + l16;
#pragma unroll
    for (int r = 0; r < 4; ++r) {
      const int m = row0 + wave * 16 + quad * 4 + r;
      const size_t idx = (size_t)m * 768 + j;
      out[idx] = acc[nt][r] + b2[j] + x2[idx];
    }
  }
}

// ---------- launch ----------
extern "C" void kernel_launch(void* const* d_in, const int* in_sizes, int n_in,
                              void* d_out, int out_size, void* d_ws, size_t ws_size,
                              hipStream_t stream) {
  const float* x       = (const float*)d_in[0];
  const float* q_extra = (const float*)d_in[1];
  const float* ln1_g   = (const float*)d_in[2];
  const float* ln1_b   = (const float*)d_in[3];
  const float* w_kv    = (const float*)d_in[4];
  const float* w_out   = (const float*)d_in[5];
  const float* b_out   = (const float*)d_in[6];
  const float* ln2_g   = (const float*)d_in[7];
  const float* ln2_b   = (const float*)d_in[8];
  const float* w1      = (const float*)d_in[9];
  const float* b1      = (const float*)d_in[10];
  const float* w2      = (const float*)d_in[11];
  const float* b2      = (const float*)d_in[12];
  float* out = (float*)d_out;

  char* ws = (char*)d_ws;
  unsigned short* xn    = (unsigned short*)(ws);
  unsigned short* kbuf  = (unsigned short*)(ws + 12582912);
  unsigned short* vtbuf = (unsigned short*)(ws + 25165824);
  unsigned short* ao    = (unsigned short*)(ws + 37748736);
  float*          x2    = (float*)(ws + 50331648);
  unsigned short* h1    = (unsigned short*)(ws + 75497472);
  unsigned short* hbuf  = xn;  // xn dead after kv GEMM; reuse for LN2 output

  ln_kernel<<<8192, 256, 0, stream>>>(x, ln1_g, ln1_b, xn);
  gemm_kv_kernel<<<dim3(24, 128), 256, 0, stream>>>(xn, w_kv, kbuf, vtbuf);
  attn_kernel<<<dim3(16, 12, 8), 256, 0, stream>>>(q_extra, kbuf, vtbuf, ao);
  gemm_outproj_kernel<<<dim3(12, 128), 256, 0, stream>>>(ao, w_out, b_out, x, x2);
  ln_kernel<<<8192, 256, 0, stream>>>(x2, ln2_g, ln2_b, hbuf);
  gemm_mlp1_kernel<<<dim3(48, 128), 256, 0, stream>>>(hbuf, w1, b1, h1);
  gemm_mlp2_kernel<<<dim3(12, 128), 256, 0, stream>>>(h1, w2, b2, x2, out);
}

// Round 3
// 443.967 us; speedup vs baseline: 3.9854x; 1.5937x over previous
//
#include <hip/hip_runtime.h>

// ---------- types ----------
typedef __attribute__((ext_vector_type(8))) short short8;
typedef __attribute__((ext_vector_type(4))) float float4v;

__device__ __forceinline__ unsigned short f2bf(float f) {
  union { unsigned int i; float f; } x; x.f = f;
  unsigned int r = x.i + 0x7fffu + ((x.i >> 16) & 1u);  // round-nearest-even
  return (unsigned short)(r >> 16);
}

// ---------- LayerNorm: one block per row of 768 ----------
__global__ void ln_kernel(const float* __restrict__ in, const float* __restrict__ g,
                          const float* __restrict__ b, unsigned short* __restrict__ out) {
  const int row = blockIdx.x, t = threadIdx.x;
  const float* xr = in + (size_t)row * 768;
  float v0 = xr[t], v1 = xr[t + 256], v2 = xr[t + 512];
  float s = v0 + v1 + v2;
  float s2 = v0 * v0 + v1 * v1 + v2 * v2;
  for (int off = 32; off > 0; off >>= 1) {
    s += __shfl_xor(s, off, 64);
    s2 += __shfl_xor(s2, off, 64);
  }
  __shared__ float red[8];
  const int wave = t >> 6, lane = t & 63;
  if (lane == 0) { red[wave] = s; red[wave + 4] = s2; }
  __syncthreads();
  s = red[0] + red[1] + red[2] + red[3];
  s2 = red[4] + red[5] + red[6] + red[7];
  const float mu = s * (1.0f / 768.0f);
  const float var = s2 * (1.0f / 768.0f) - mu * mu;
  const float rstd = rsqrtf(var + 1e-5f);
  unsigned short* orow = out + (size_t)row * 768;
  orow[t]       = f2bf((v0 - mu) * rstd * g[t]       + b[t]);
  orow[t + 256] = f2bf((v1 - mu) * rstd * g[t + 256] + b[t + 256]);
  orow[t + 512] = f2bf((v2 - mu) * rstd * g[t + 512] + b[t + 512]);
}

// ---------- weight transpose+convert: f32 (K,N) -> bf16 (N,K) ----------
__global__ void wtrans_kernel(const float* __restrict__ in, unsigned short* __restrict__ out,
                              int K, int N) {
  __shared__ float tile[32][33];
  const int k0 = blockIdx.y * 32, n0 = blockIdx.x * 32;
  const int tr = threadIdx.x >> 5, tc = threadIdx.x & 31;
#pragma unroll
  for (int i = 0; i < 4; ++i)
    tile[tr + i * 8][tc] = in[(size_t)(k0 + tr + i * 8) * N + n0 + tc];
  __syncthreads();
#pragma unroll
  for (int i = 0; i < 4; ++i)
    out[(size_t)(n0 + tr + i * 8) * K + k0 + tc] = f2bf(tile[tc][tr + i * 8]);
}

// ---------- GEMM core: 128x128 tile, 256 threads, global_load_lds staging ----------
// A: bf16 row-major MxK (lda). Bt: bf16 row-major NxK (ldb=K).
// LDS tiles: As[128][32], Bs[128][32] bf16, linear (m97 layout — no padding, required
// by global_load_lds's wave-uniform-base + lane*16 destination rule).
// Wave w: rows [wr*64, +64), cols [wc*64, +64); 4x4 16x16 acc frags.
__device__ __forceinline__ void gemm128(
    const unsigned short* __restrict__ A, int lda,
    const unsigned short* __restrict__ Bt, int ldb, int K,
    int row0, int col0,
    unsigned short* As, unsigned short* Bs,
    float4v acc[4][4]) {
  const int t = threadIdx.x, lane = t & 63, wave = t >> 6;
  const int quad = lane >> 4, l16 = lane & 15;
  const int wr = wave >> 1, wc = wave & 1;
  const int sr = lane >> 2;        // staging row within 16-row chunk
  const int sc = (lane & 3) * 8;   // staging col (elements)
#pragma unroll
  for (int mt = 0; mt < 4; ++mt)
#pragma unroll
    for (int nt = 0; nt < 4; ++nt) acc[mt][nt] = (float4v)(0.0f);

  for (int kk = 0; kk < K; kk += 32) {
    __syncthreads();  // previous iteration's readers done
#pragma unroll
    for (int j = 0; j < 2; ++j) {
      const int chunk = wave * 2 + j;          // 0..7, 16 rows each
      const int r = chunk * 16 + sr;
      __builtin_amdgcn_global_load_lds(
          (const __attribute__((address_space(1))) unsigned int*)(A + (size_t)(row0 + r) * lda + kk + sc),
          (__attribute__((address_space(3))) unsigned int*)(As + chunk * 512),
          16, 0, 0);
      __builtin_amdgcn_global_load_lds(
          (const __attribute__((address_space(1))) unsigned int*)(Bt + (size_t)(col0 + r) * ldb + kk + sc),
          (__attribute__((address_space(3))) unsigned int*)(Bs + chunk * 512),
          16, 0, 0);
    }
    __syncthreads();  // staging complete (compiler drains vmcnt before barrier)
    short8 af[4], bfv[4];
#pragma unroll
    for (int i = 0; i < 4; ++i) {
      af[i]  = *(const short8*)(As + (wr * 64 + i * 16 + l16) * 32 + quad * 8);
      bfv[i] = *(const short8*)(Bs + (wc * 64 + i * 16 + l16) * 32 + quad * 8);
    }
#pragma unroll
    for (int mt = 0; mt < 4; ++mt)
#pragma unroll
      for (int nt = 0; nt < 4; ++nt)
        acc[mt][nt] = __builtin_amdgcn_mfma_f32_16x16x32_bf16(af[mt], bfv[nt], acc[mt][nt], 0, 0, 0);
  }
}

#define GEMM128_PROLOGUE                                         \
  __shared__ unsigned short As[128 * 32];                        \
  __shared__ unsigned short Bs[128 * 32];                        \
  float4v acc[4][4];                                             \
  const int col0 = blockIdx.x * 128, row0 = blockIdx.y * 128;    \
  const int t = threadIdx.x, lane = t & 63, wave = t >> 6;       \
  const int quad = lane >> 4, l16 = lane & 15;                   \
  const int wr = wave >> 1, wc = wave & 1; (void)t;

// ---------- kv GEMM: xn @ w_kv -> k (B,H,N,DH), v TRANSPOSED (B,H,DH,N) ----------
__global__ void gemm_kv_kernel(const unsigned short* __restrict__ xn,
                               const unsigned short* __restrict__ wkvt,
                               unsigned short* __restrict__ kbuf,
                               unsigned short* __restrict__ vtbuf) {
  GEMM128_PROLOGUE
  gemm128(xn, 768, wkvt, 768, 768, row0, col0, As, Bs, acc);
#pragma unroll
  for (int mt = 0; mt < 4; ++mt)
#pragma unroll
    for (int nt = 0; nt < 4; ++nt) {
      const int j = col0 + wc * 64 + nt * 16 + l16;
#pragma unroll
      for (int r = 0; r < 4; ++r) {
        const int m = row0 + wr * 64 + mt * 16 + quad * 4 + r;
        const int bb = m >> 10, n = m & 1023;
        const float c = acc[mt][nt][r];
        if (j < 768) {
          const int hh = j >> 6, d = j & 63;
          kbuf[((size_t)(bb * 12 + hh) * 1024 + n) * 64 + d] = f2bf(c);
        } else {
          const int j2 = j - 768, hh = j2 >> 6, d = j2 & 63;
          vtbuf[((size_t)(bb * 12 + hh) * 64 + d) * 1024 + n] = f2bf(c);
        }
      }
    }
}

// ---------- MFMA flash attention (unchanged from round 2) ----------
#define AST 72
__global__ void attn_kernel(const float* __restrict__ q_extra,
                            const unsigned short* __restrict__ kbuf,
                            const unsigned short* __restrict__ vtbuf,
                            unsigned short* __restrict__ ao) {
  __shared__ unsigned short Ks[64 * AST];
  __shared__ unsigned short Vs[64 * AST];
  __shared__ unsigned short Ps[4][16 * AST];
  const int b = blockIdx.z, h = blockIdx.y, q0 = blockIdx.x * 64;
  const int t = threadIdx.x, lane = t & 63, wave = t >> 6;
  const int quad = lane >> 4, l16 = lane & 15;

  short8 qf0, qf1;
  {
    const float* qp = q_extra +
        ((size_t)((b * 1024 + q0 + wave * 16 + l16) * 12 + h)) * 64 + quad * 8;
    float4 a0 = *(const float4*)(qp);
    float4 a1 = *(const float4*)(qp + 4);
    float4 c0 = *(const float4*)(qp + 32);
    float4 c1 = *(const float4*)(qp + 36);
    qf0[0] = (short)f2bf(a0.x * 0.125f); qf0[1] = (short)f2bf(a0.y * 0.125f);
    qf0[2] = (short)f2bf(a0.z * 0.125f); qf0[3] = (short)f2bf(a0.w * 0.125f);
    qf0[4] = (short)f2bf(a1.x * 0.125f); qf0[5] = (short)f2bf(a1.y * 0.125f);
    qf0[6] = (short)f2bf(a1.z * 0.125f); qf0[7] = (short)f2bf(a1.w * 0.125f);
    qf1[0] = (short)f2bf(c0.x * 0.125f); qf1[1] = (short)f2bf(c0.y * 0.125f);
    qf1[2] = (short)f2bf(c0.z * 0.125f); qf1[3] = (short)f2bf(c0.w * 0.125f);
    qf1[4] = (short)f2bf(c1.x * 0.125f); qf1[5] = (short)f2bf(c1.y * 0.125f);
    qf1[6] = (short)f2bf(c1.z * 0.125f); qf1[7] = (short)f2bf(c1.w * 0.125f);
  }

  const unsigned short* kb = kbuf + (size_t)(b * 12 + h) * 65536;
  const unsigned short* vb = vtbuf + (size_t)(b * 12 + h) * 65536;
  const int srow = t >> 2, scol = (t & 3) * 16;

  float m_r[4] = {-1e30f, -1e30f, -1e30f, -1e30f};
  float l_r[4] = {0.f, 0.f, 0.f, 0.f};
  float4v acc[4];
  acc[0] = (float4v)(0.f); acc[1] = (float4v)(0.f);
  acc[2] = (float4v)(0.f); acc[3] = (float4v)(0.f);

  for (int c = 0; c < 16; ++c) {
    const int key0 = c * 64;
    __syncthreads();
    {
      const unsigned short* ksrc = kb + (size_t)(key0 + srow) * 64 + scol;
      *(short8*)(Ks + srow * AST + scol)     = *(const short8*)(ksrc);
      *(short8*)(Ks + srow * AST + scol + 8) = *(const short8*)(ksrc + 8);
      const unsigned short* vsrc = vb + (size_t)srow * 1024 + key0 + scol;
      *(short8*)(Vs + srow * AST + scol)     = *(const short8*)(vsrc);
      *(short8*)(Vs + srow * AST + scol + 8) = *(const short8*)(vsrc + 8);
    }
    __syncthreads();

    float4v s[4];
#pragma unroll
    for (int kt = 0; kt < 4; ++kt) {
      const unsigned short* kr = Ks + (kt * 16 + l16) * AST;
      short8 kf0 = *(const short8*)(kr + quad * 8);
      short8 kf1 = *(const short8*)(kr + 32 + quad * 8);
      float4v a = (float4v)(0.f);
      a = __builtin_amdgcn_mfma_f32_16x16x32_bf16(qf0, kf0, a, 0, 0, 0);
      a = __builtin_amdgcn_mfma_f32_16x16x32_bf16(qf1, kf1, a, 0, 0, 0);
      s[kt] = a;
    }

    float mx[4];
#pragma unroll
    for (int r = 0; r < 4; ++r)
      mx[r] = fmaxf(fmaxf(s[0][r], s[1][r]), fmaxf(s[2][r], s[3][r]));
#pragma unroll
    for (int off = 1; off < 16; off <<= 1) {
#pragma unroll
      for (int r = 0; r < 4; ++r) mx[r] = fmaxf(mx[r], __shfl_xor(mx[r], off, 64));
    }
    float alpha[4], sum[4];
#pragma unroll
    for (int r = 0; r < 4; ++r) {
      const float mn = fmaxf(m_r[r], mx[r]);
      alpha[r] = __expf(m_r[r] - mn);
      m_r[r] = mn;
      sum[r] = 0.f;
    }
    unsigned short* pw = Ps[wave];
#pragma unroll
    for (int kt = 0; kt < 4; ++kt) {
#pragma unroll
      for (int r = 0; r < 4; ++r) {
        const float p = __expf(s[kt][r] - m_r[r]);
        sum[r] += p;
        pw[(quad * 4 + r) * AST + kt * 16 + l16] = f2bf(p);
      }
    }
#pragma unroll
    for (int off = 1; off < 16; off <<= 1) {
#pragma unroll
      for (int r = 0; r < 4; ++r) sum[r] += __shfl_xor(sum[r], off, 64);
    }
#pragma unroll
    for (int r = 0; r < 4; ++r) l_r[r] = l_r[r] * alpha[r] + sum[r];
#pragma unroll
    for (int nt = 0; nt < 4; ++nt) {
#pragma unroll
      for (int r = 0; r < 4; ++r) acc[nt][r] *= alpha[r];
    }

    short8 pf0 = *(const short8*)(pw + l16 * AST + quad * 8);
    short8 pf1 = *(const short8*)(pw + l16 * AST + 32 + quad * 8);
#pragma unroll
    for (int nt = 0; nt < 4; ++nt) {
      const unsigned short* vr = Vs + (nt * 16 + l16) * AST;
      short8 vf0 = *(const short8*)(vr + quad * 8);
      short8 vf1 = *(const short8*)(vr + 32 + quad * 8);
      acc[nt] = __builtin_amdgcn_mfma_f32_16x16x32_bf16(pf0, vf0, acc[nt], 0, 0, 0);
      acc[nt] = __builtin_amdgcn_mfma_f32_16x16x32_bf16(pf1, vf1, acc[nt], 0, 0, 0);
    }
  }

  float inv[4];
#pragma unroll
  for (int r = 0; r < 4; ++r) inv[r] = 1.0f / l_r[r];
#pragma unroll
  for (int nt = 0; nt < 4; ++nt) {
#pragma unroll
    for (int r = 0; r < 4; ++r) {
      const int m = q0 + wave * 16 + quad * 4 + r;
      ao[(size_t)(b * 1024 + m) * 768 + h * 64 + nt * 16 + l16] =
          f2bf(acc[nt][r] * inv[r]);
    }
  }
}

// ---------- out-proj GEMM + bias + residual -> x2 (f32) ----------
__global__ void gemm_outproj_kernel(const unsigned short* __restrict__ ao,
                                    const unsigned short* __restrict__ woutt,
                                    const float* __restrict__ b_out,
                                    const float* __restrict__ x,
                                    float* __restrict__ x2) {
  GEMM128_PROLOGUE
  gemm128(ao, 768, woutt, 768, 768, row0, col0, As, Bs, acc);
#pragma unroll
  for (int mt = 0; mt < 4; ++mt)
#pragma unroll
    for (int nt = 0; nt < 4; ++nt) {
      const int j = col0 + wc * 64 + nt * 16 + l16;
#pragma unroll
      for (int r = 0; r < 4; ++r) {
        const int m = row0 + wr * 64 + mt * 16 + quad * 4 + r;
        const size_t idx = (size_t)m * 768 + j;
        x2[idx] = acc[mt][nt][r] + b_out[j] + x[idx];
      }
    }
}

// ---------- MLP1 GEMM + bias + exact GELU -> h1 (bf16) ----------
__global__ void gemm_mlp1_kernel(const unsigned short* __restrict__ h,
                                 const unsigned short* __restrict__ w1t,
                                 const float* __restrict__ b1,
                                 unsigned short* __restrict__ h1) {
  GEMM128_PROLOGUE
  gemm128(h, 768, w1t, 768, 768, row0, col0, As, Bs, acc);
#pragma unroll
  for (int mt = 0; mt < 4; ++mt)
#pragma unroll
    for (int nt = 0; nt < 4; ++nt) {
      const int j = col0 + wc * 64 + nt * 16 + l16;
#pragma unroll
      for (int r = 0; r < 4; ++r) {
        const int m = row0 + wr * 64 + mt * 16 + quad * 4 + r;
        const float y = acc[mt][nt][r] + b1[j];
        const float ge = 0.5f * y * (1.0f + erff(y * 0.70710678118654752f));
        h1[(size_t)m * 3072 + j] = f2bf(ge);
      }
    }
}

// ---------- MLP2 GEMM + bias + residual -> out (f32) ----------
__global__ void gemm_mlp2_kernel(const unsigned short* __restrict__ h1,
                                 const unsigned short* __restrict__ w2t,
                                 const float* __restrict__ b2,
                                 const float* __restrict__ x2,
                                 float* __restrict__ out) {
  GEMM128_PROLOGUE
  gemm128(h1, 3072, w2t, 3072, 3072, row0, col0, As, Bs, acc);
#pragma unroll
  for (int mt = 0; mt < 4; ++mt)
#pragma unroll
    for (int nt = 0; nt < 4; ++nt) {
      const int j = col0 + wc * 64 + nt * 16 + l16;
#pragma unroll
      for (int r = 0; r < 4; ++r) {
        const int m = row0 + wr * 64 + mt * 16 + quad * 4 + r;
        const size_t idx = (size_t)m * 768 + j;
        out[idx] = acc[mt][nt][r] + b2[j] + x2[idx];
      }
    }
}

// ---------- launch ----------
extern "C" void kernel_launch(void* const* d_in, const int* in_sizes, int n_in,
                              void* d_out, int out_size, void* d_ws, size_t ws_size,
                              hipStream_t stream) {
  const float* x       = (const float*)d_in[0];
  const float* q_extra = (const float*)d_in[1];
  const float* ln1_g   = (const float*)d_in[2];
  const float* ln1_b   = (const float*)d_in[3];
  const float* w_kv    = (const float*)d_in[4];
  const float* w_out   = (const float*)d_in[5];
  const float* b_out   = (const float*)d_in[6];
  const float* ln2_g   = (const float*)d_in[7];
  const float* ln2_b   = (const float*)d_in[8];
  const float* w1      = (const float*)d_in[9];
  const float* b1      = (const float*)d_in[10];
  const float* w2      = (const float*)d_in[11];
  const float* b2      = (const float*)d_in[12];
  float* out = (float*)d_out;

  char* ws = (char*)d_ws;
  unsigned short* xn    = (unsigned short*)(ws);
  unsigned short* kbuf  = (unsigned short*)(ws + 12582912);
  unsigned short* vtbuf = (unsigned short*)(ws + 25165824);
  unsigned short* ao    = (unsigned short*)(ws + 37748736);
  float*          x2    = (float*)(ws + 50331648);
  unsigned short* h1    = (unsigned short*)(ws + 75497472);
  unsigned short* hbuf  = xn;   // xn dead after kv GEMM
  // transposed bf16 weights in dead regions:
  unsigned short* wkvt  = ao;                          // used before attn writes ao
  unsigned short* woutt = h1;                          // used before mlp1 writes h1
  unsigned short* w1t   = kbuf;                        // kbuf dead after attn
  unsigned short* w2t   = vtbuf;                       // vtbuf dead after attn

  ln_kernel<<<8192, 256, 0, stream>>>(x, ln1_g, ln1_b, xn);
  wtrans_kernel<<<dim3(48, 24), 256, 0, stream>>>(w_kv, wkvt, 768, 1536);
  wtrans_kernel<<<dim3(24, 24), 256, 0, stream>>>(w_out, woutt, 768, 768);
  gemm_kv_kernel<<<dim3(12, 64), 256, 0, stream>>>(xn, wkvt, kbuf, vtbuf);
  attn_kernel<<<dim3(16, 12, 8), 256, 0, stream>>>(q_extra, kbuf, vtbuf, ao);
  wtrans_kernel<<<dim3(96, 24), 256, 0, stream>>>(w1, w1t, 768, 3072);
  wtrans_kernel<<<dim3(24, 96), 256, 0, stream>>>(w2, w2t, 3072, 768);
  gemm_outproj_kernel<<<dim3(6, 64), 256, 0, stream>>>(ao, woutt, b_out, x, x2);
  ln_kernel<<<8192, 256, 0, stream>>>(x2, ln2_g, ln2_b, hbuf);
  gemm_mlp1_kernel<<<dim3(24, 64), 256, 0, stream>>>(hbuf, w1t, b1, h1);
  gemm_mlp2_kernel<<<dim3(6, 64), 256, 0, stream>>>(h1, w2t, b2, x2, out);
}